// Round 15
// baseline (358.343 us; speedup 1.0000x reference)
//
#include <hip/hip_runtime.h>

typedef unsigned short ushort_t;
typedef unsigned int uint_t;

// ---------------------------------------------------------------------------
// GCN 3-layer forward.  N=50000, E=800000, D=H=128, C=40.
// Round 15: (1) bsum+bscan+rowptr collapsed into ONE decoupled-lookback scan
// dispatch (196 blocks, all resident -> no deadlock; device-scope atomics).
// Dispatch count 13 -> 11; per-dispatch overhead ~8-10 us is now first-order.
// (2) agg128 edge loop unrolled 16 (was 8); agg40 rebuilt as uniform
// full-wave (one wave/dst, scalar csr, no divergence) with unroll 16.
// Ascending-j FMA order preserved -> bitwise-identical numerics.
// ws layout: [deg:N int][partials:nb u64][rowptr:N+1][cursor:N][dinv:N f32]
//            [csr:E int2][bufA:N*128*4 B][bufB:N*128 f32]
// ---------------------------------------------------------------------------

__global__ void k_deg_count(const int* __restrict__ ei, int* __restrict__ deg, int E) {
    int e = blockIdx.x * blockDim.x + threadIdx.x;
    if (e < E) atomicAdd(&deg[ei[E + e]], 1);   // dst = ei[E+e]
}

// Single-dispatch scan: per-block reduce -> decoupled lookback over packed
// (sum<<2 | state) partials -> block-local scan -> rowptr/cursor/dinv.
// partials pre-zeroed by the same memset as deg.  All 196 blocks co-resident.
__global__ __launch_bounds__(256) void k_scan(
        const int* __restrict__ deg, unsigned long long* __restrict__ partials,
        int* __restrict__ rowptr, int* __restrict__ cursor,
        float* __restrict__ dinv, int n) {
    __shared__ int s[256];
    __shared__ int sprefix;
    const int b = blockIdx.x, t = threadIdx.x;
    const int i = b * 256 + t;
    int v = (i < n) ? deg[i] : 0;
    s[t] = v;
    __syncthreads();
    for (int off = 1; off < 256; off <<= 1) {
        int u = (t >= off) ? s[t - off] : 0;
        __syncthreads();
        s[t] += u;
        __syncthreads();
    }
    if (t == 0) {
        unsigned long long bs = (unsigned long long)s[255];
        __hip_atomic_store(&partials[b], (bs << 2) | 1ull,
                           __ATOMIC_RELEASE, __HIP_MEMORY_SCOPE_AGENT);
        long long acc = 0;
        for (int k = b - 1; k >= 0; ) {
            unsigned long long p = __hip_atomic_load(&partials[k],
                    __ATOMIC_ACQUIRE, __HIP_MEMORY_SCOPE_AGENT);
            unsigned st = (unsigned)(p & 3ull);
            if (st == 0) continue;          // spin until block k publishes
            acc += (long long)(p >> 2);
            if (st == 2) break;             // prefix-inclusive: done
            --k;                            // aggregate only: keep walking
        }
        __hip_atomic_store(&partials[b],
                (((unsigned long long)(acc + (long long)bs)) << 2) | 2ull,
                __ATOMIC_RELEASE, __HIP_MEMORY_SCOPE_AGENT);
        sprefix = (int)acc;
    }
    __syncthreads();
    if (i < n) {
        int ex = sprefix + s[t] - v;        // exclusive prefix
        rowptr[i] = ex;
        cursor[i] = ex;
        dinv[i] = rsqrtf((float)(v + 1));   // +1 self-loop
        if (i == n - 1) rowptr[n] = ex + v;
    }
}

// XCD-partitioned scatter (R12): block b serves dst in [(b&7)*n/8, ...).
__global__ __launch_bounds__(256) void k_fill(const int* __restrict__ ei,
                                              int* __restrict__ cursor,
                                              const float* __restrict__ dinv,
                                              int2* __restrict__ csr, int E, int n) {
    const int xcd = blockIdx.x & 7;
    const int e = (blockIdx.x >> 3) * 256 + threadIdx.x;
    if (e >= E) return;
    int d = ei[E + e];
    const int lo = (int)(((long long)xcd * n) >> 3);
    const int hi = (int)(((long long)(xcd + 1) * n) >> 3);
    if (d < lo || d >= hi) return;
    int s = ei[e];
    int pos = atomicAdd(&cursor[d], 1);
    int2 p;
    p.x = s;
    p.y = __float_as_int(dinv[s] * dinv[d]);
    csr[pos] = p;
}

__device__ __forceinline__ ushort_t f2bf_rne(float f) {
    uint_t u = __float_as_uint(f);
    u += 0x7fffu + ((u >> 16) & 1u);
    return (ushort_t)(u >> 16);
}
__device__ __forceinline__ float bflo(uint_t u) {
    return __uint_as_float(u << 16);
}
__device__ __forceinline__ float bfhi(uint_t u) {
    return __uint_as_float(u & 0xffff0000u);
}

// ---- Ybf16[N,128] = X[N,128] @ W[128,128].  BM=128, BK=32; 8x8 microtile.
__global__ __launch_bounds__(256) void k_gemm128(const float* __restrict__ X,
                                                 const float* __restrict__ W,
                                                 ushort_t* __restrict__ Y, int N) {
    __shared__ float sX[32][132];
    __shared__ float sW[32][128];
    const int tid = threadIdx.x;
    const int bm = blockIdx.x * 128;
    const int m0 = (tid >> 4) * 8;
    const int c4 = (tid & 15) * 4;
    const int xf = tid & 7;
    float acc[8][8] = {};
    for (int k0 = 0; k0 < 128; k0 += 32) {
        #pragma unroll
        for (int it = 0; it < 4; ++it) {
            int i = tid + it * 256;
            int row = bm + (i >> 3);
            int rc = min(row, N - 1);
            float4 v = *(const float4*)(X + (size_t)rc * 128 + k0 + xf * 4);
            int m = i >> 3;
            sX[xf * 4 + 0][m] = v.x;
            sX[xf * 4 + 1][m] = v.y;
            sX[xf * 4 + 2][m] = v.z;
            sX[xf * 4 + 3][m] = v.w;
        }
        #pragma unroll
        for (int it = 0; it < 4; ++it) {
            int i = tid + it * 256;
            int wr = i >> 5;
            int wf = i & 31;
            *(float4*)(&sW[wr][wf * 4]) =
                *(const float4*)(W + (size_t)(k0 + wr) * 128 + wf * 4);
        }
        __syncthreads();
        #pragma unroll
        for (int kk = 0; kk < 32; ++kk) {
            float4 a0 = *(const float4*)(&sX[kk][m0]);
            float4 a1 = *(const float4*)(&sX[kk][m0 + 4]);
            float4 b0 = *(const float4*)(&sW[kk][c4]);
            float4 b1 = *(const float4*)(&sW[kk][64 + c4]);
            float av[8] = {a0.x, a0.y, a0.z, a0.w, a1.x, a1.y, a1.z, a1.w};
            float bv[8] = {b0.x, b0.y, b0.z, b0.w, b1.x, b1.y, b1.z, b1.w};
            #pragma unroll
            for (int r = 0; r < 8; ++r)
                #pragma unroll
                for (int c = 0; c < 8; ++c)
                    acc[r][c] = fmaf(av[r], bv[c], acc[r][c]);
        }
        __syncthreads();
    }
    #pragma unroll
    for (int r = 0; r < 8; ++r) {
        int row = bm + m0 + r;
        if (row < N) {
            ushort4 o0 = {f2bf_rne(acc[r][0]), f2bf_rne(acc[r][1]),
                          f2bf_rne(acc[r][2]), f2bf_rne(acc[r][3])};
            ushort4 o1 = {f2bf_rne(acc[r][4]), f2bf_rne(acc[r][5]),
                          f2bf_rne(acc[r][6]), f2bf_rne(acc[r][7])};
            *(ushort4*)(Y + (size_t)row * 128 + c4)      = o0;
            *(ushort4*)(Y + (size_t)row * 128 + 64 + c4) = o1;
        }
    }
}

// ---- Ybf16[N,40 (stride 64)] = X[N,128] @ W[128,40].  BM=128, BK=32. ----
__global__ __launch_bounds__(256) void k_gemm40(const float* __restrict__ X,
                                                const float* __restrict__ W,
                                                ushort_t* __restrict__ Y, int N) {
    __shared__ float sX[32][132];
    __shared__ float sW[32][40];
    const int tid = threadIdx.x;
    const int bm = blockIdx.x * 128;
    const int m0 = (tid >> 3) * 4;
    const int n0 = (tid & 7) * 5;
    const int xf = tid & 7;
    float acc[4][5] = {};
    for (int k0 = 0; k0 < 128; k0 += 32) {
        #pragma unroll
        for (int it = 0; it < 4; ++it) {
            int i = tid + it * 256;
            int row = bm + (i >> 3);
            int rc = min(row, N - 1);
            float4 v = *(const float4*)(X + (size_t)rc * 128 + k0 + xf * 4);
            int m = i >> 3;
            sX[xf * 4 + 0][m] = v.x;
            sX[xf * 4 + 1][m] = v.y;
            sX[xf * 4 + 2][m] = v.z;
            sX[xf * 4 + 3][m] = v.w;
        }
        for (int i = tid; i < 320; i += 256) {
            int wr = i / 10;
            int wf = i - wr * 10;
            *(float4*)(&sW[wr][wf * 4]) =
                *(const float4*)(W + (size_t)(k0 + wr) * 40 + wf * 4);
        }
        __syncthreads();
        #pragma unroll
        for (int kk = 0; kk < 32; ++kk) {
            float4 a = *(const float4*)(&sX[kk][m0]);
            float av[4] = {a.x, a.y, a.z, a.w};
            #pragma unroll
            for (int c = 0; c < 5; ++c) {
                float b = sW[kk][n0 + c];
                #pragma unroll
                for (int r = 0; r < 4; ++r)
                    acc[r][c] = fmaf(av[r], b, acc[r][c]);
            }
        }
        __syncthreads();
    }
    #pragma unroll
    for (int r = 0; r < 4; ++r) {
        int row = bm + m0 + r;
        if (row < N) {
            #pragma unroll
            for (int c = 0; c < 5; ++c)
                Y[(size_t)row * 64 + n0 + c] = f2bf_rne(acc[r][c]);
        }
    }
}

// Uniform full-wave agg, F=128 bf16.  One wave per dst; lane i owns uint i of
// the 256-B row.  csr (src,w) batches are independent scalar loads.  Unroll 16.
template <bool RELU>
__global__ __launch_bounds__(256) void k_agg128(
        const ushort_t* __restrict__ XW, const int* __restrict__ rowptr,
        const int2* __restrict__ csr, const float* __restrict__ dinv,
        const float* __restrict__ bias, float* __restrict__ out, int n) {
    const int lane = threadIdx.x & 63;
    const int wv = __builtin_amdgcn_readfirstlane(threadIdx.x >> 6);
    const int d = blockIdx.x * 4 + wv;
    if (d >= n) return;
    const uint_t* xw = (const uint_t*)XW;           // row stride 64 uints
    float dv = dinv[d];
    float w0 = dv * dv;
    uint_t sq = xw[(size_t)d * 64 + lane];
    float2 a;
    a.x = w0 * bflo(sq);
    a.y = w0 * bfhi(sq);
    int j = rowptr[d], end = rowptr[d + 1];
    for (; j + 16 <= end; j += 16) {
        int2 p[16];
        #pragma unroll
        for (int q = 0; q < 16; ++q) p[q] = csr[j + q];
        uint_t u[16];
        #pragma unroll
        for (int q = 0; q < 16; ++q) u[q] = xw[(size_t)p[q].x * 64 + lane];
        #pragma unroll
        for (int q = 0; q < 16; ++q) {
            float we = __int_as_float(p[q].y);
            a.x = fmaf(we, bflo(u[q]), a.x);
            a.y = fmaf(we, bfhi(u[q]), a.y);
        }
    }
    for (; j + 8 <= end; j += 8) {
        int2 p[8];
        #pragma unroll
        for (int q = 0; q < 8; ++q) p[q] = csr[j + q];
        uint_t u[8];
        #pragma unroll
        for (int q = 0; q < 8; ++q) u[q] = xw[(size_t)p[q].x * 64 + lane];
        #pragma unroll
        for (int q = 0; q < 8; ++q) {
            float we = __int_as_float(p[q].y);
            a.x = fmaf(we, bflo(u[q]), a.x);
            a.y = fmaf(we, bfhi(u[q]), a.y);
        }
    }
    for (; j < end; ++j) {
        int2 p = csr[j];
        float we = __int_as_float(p.y);
        uint_t u = xw[(size_t)p.x * 64 + lane];
        a.x = fmaf(we, bflo(u), a.x);
        a.y = fmaf(we, bfhi(u), a.y);
    }
    float2 b = ((const float2*)bias)[lane];
    a.x += b.x; a.y += b.y;
    if (RELU) {
        a.x = fmaxf(a.x, 0.f);
        a.y = fmaxf(a.y, 0.f);
    }
    ((float2*)out)[(size_t)d * 64 + lane] = a;
}

// Uniform full-wave agg, F=40 bf16 (rows stride 32 uints = one 128-B line).
// One wave per dst; lanes 0..19 active on data, scalar csr, no divergence.
__global__ __launch_bounds__(256) void k_agg40(
        const ushort_t* __restrict__ XW, const int* __restrict__ rowptr,
        const int2* __restrict__ csr, const float* __restrict__ dinv,
        const float* __restrict__ bias, float* __restrict__ out, int n) {
    const int lane = threadIdx.x & 63;
    const int wv = __builtin_amdgcn_readfirstlane(threadIdx.x >> 6);
    const int d = blockIdx.x * 4 + wv;
    if (d >= n || lane >= 20) return;
    const uint_t* xw = (const uint_t*)XW;       // row stride 32 uints
    float dv = dinv[d];
    float w0 = dv * dv;
    uint_t sq = xw[(size_t)d * 32 + lane];
    float2 a;
    a.x = w0 * bflo(sq);
    a.y = w0 * bfhi(sq);
    int j = rowptr[d], end = rowptr[d + 1];
    for (; j + 16 <= end; j += 16) {
        int2 p[16];
        #pragma unroll
        for (int q = 0; q < 16; ++q) p[q] = csr[j + q];
        uint_t u[16];
        #pragma unroll
        for (int q = 0; q < 16; ++q) u[q] = xw[(size_t)p[q].x * 32 + lane];
        #pragma unroll
        for (int q = 0; q < 16; ++q) {
            float we = __int_as_float(p[q].y);
            a.x = fmaf(we, bflo(u[q]), a.x);
            a.y = fmaf(we, bfhi(u[q]), a.y);
        }
    }
    for (; j + 8 <= end; j += 8) {
        int2 p[8];
        #pragma unroll
        for (int q = 0; q < 8; ++q) p[q] = csr[j + q];
        uint_t u[8];
        #pragma unroll
        for (int q = 0; q < 8; ++q) u[q] = xw[(size_t)p[q].x * 32 + lane];
        #pragma unroll
        for (int q = 0; q < 8; ++q) {
            float we = __int_as_float(p[q].y);
            a.x = fmaf(we, bflo(u[q]), a.x);
            a.y = fmaf(we, bfhi(u[q]), a.y);
        }
    }
    for (; j < end; ++j) {
        int2 p = csr[j];
        float we = __int_as_float(p.y);
        uint_t u = xw[(size_t)p.x * 32 + lane];
        a.x = fmaf(we, bflo(u), a.x);
        a.y = fmaf(we, bfhi(u), a.y);
    }
    float2 b = ((const float2*)bias)[lane];
    a.x += b.x; a.y += b.y;
    ((float2*)out)[(size_t)d * 20 + lane] = a;
}

static inline int cdiv(long long a, int b) { return (int)((a + b - 1) / b); }

extern "C" void kernel_launch(void* const* d_in, const int* in_sizes, int n_in,
                              void* d_out, int out_size, void* d_ws, size_t ws_size,
                              hipStream_t stream) {
    const float* x  = (const float*)d_in[0];
    const int*   ei = (const int*)d_in[1];
    const float* W1 = (const float*)d_in[2];
    const float* b1 = (const float*)d_in[3];
    const float* W2 = (const float*)d_in[4];
    const float* b2 = (const float*)d_in[5];
    const float* W3 = (const float*)d_in[6];
    const float* b3 = (const float*)d_in[7];
    float* out = (float*)d_out;

    const int N = in_sizes[0] / 128;   // 50000
    const int E = in_sizes[1] / 2;     // 800000
    const int nb = cdiv(N, 256);       // 196 scan blocks

    char* ws = (char*)d_ws;
    int*   deg    = (int*)ws;                 ws += (size_t)N * 4;        // N*4 % 8 == 0
    unsigned long long* partials = (unsigned long long*)ws;
                                              ws += (size_t)nb * 8;
    int*   rowptr = (int*)ws;                 ws += (size_t)(N + 1) * 4;
    int*   cursor = (int*)ws;                 ws += (size_t)N * 4;
    float* dinv   = (float*)ws;               ws += (size_t)N * 4;
    ws = (char*)(((uintptr_t)ws + 127) & ~(uintptr_t)127);
    int2*  csr    = (int2*)ws;                ws += (size_t)E * 8;
    char*  bufA   = ws;                       ws += (size_t)N * 128 * 4;
    float* bufB   = (float*)ws;

    const int BT = 256;

    // CSR build: memset covers deg AND partials (contiguous).
    hipMemsetAsync(deg, 0, (size_t)N * 4 + (size_t)nb * 8, stream);
    k_deg_count<<<cdiv(E, BT), BT, 0, stream>>>(ei, deg, E);
    k_scan<<<nb, 256, 0, stream>>>(deg, partials, rowptr, cursor, dinv, N);
    k_fill<<<cdiv(E, BT) * 8, 256, 0, stream>>>(ei, cursor, dinv, csr, E, N);

    // layer 1
    k_gemm128<<<cdiv(N, 128), 256, 0, stream>>>(x, W1, (ushort_t*)bufA, N);
    k_agg128<true><<<cdiv(N, 4), 256, 0, stream>>>((const ushort_t*)bufA, rowptr, csr, dinv, b1, bufB, N);
    // layer 2
    k_gemm128<<<cdiv(N, 128), 256, 0, stream>>>(bufB, W2, (ushort_t*)bufA, N);
    k_agg128<true><<<cdiv(N, 4), 256, 0, stream>>>((const ushort_t*)bufA, rowptr, csr, dinv, b2, bufB, N);
    // layer 3
    k_gemm40<<<cdiv(N, 128), 256, 0, stream>>>(bufB, W3, (ushort_t*)bufA, N);
    k_agg40<<<cdiv(N, 4), 256, 0, stream>>>((const ushort_t*)bufA, rowptr, csr, dinv, b3, out, N);
}

// Round 16
// 328.081 us; speedup vs baseline: 1.0922x; 1.0922x over previous
//
#include <hip/hip_runtime.h>

typedef unsigned short ushort_t;
typedef unsigned int uint_t;

// ---------------------------------------------------------------------------
// GCN 3-layer forward.  N=50000, E=800000, D=H=128, C=40.
// Round 16: R14 kernel set (proven 321.8 us) + single-dispatch scan with
// WAVE-PARALLEL lookback (R15's serial lookback cost ~+40 us makespan —
// reverted).  Wave 0 loads 64 predecessor partials at once, ballots for the
// nearest prefix-inclusive, shuffle-reduces -> <=4 rounds for 196 blocks.
// Dispatches 12 -> 10.  agg128 unroll 8, agg40 half-wave (R14 forms).
// ws layout: [deg:N int][partials:nb u64][rowptr:N+1][cursor:N][dinv:N f32]
//            [csr:E int2][bufA:N*128*4 B][bufB:N*128 f32]
// ---------------------------------------------------------------------------

__global__ void k_deg_count(const int* __restrict__ ei, int* __restrict__ deg, int E) {
    int e = blockIdx.x * blockDim.x + threadIdx.x;
    if (e < E) atomicAdd(&deg[ei[E + e]], 1);   // dst = ei[E+e]
}

// Single-dispatch scan, wave-parallel decoupled lookback.
// partials[b] = (sum << 2) | state;  state: 0 unpublished, 1 aggregate, 2 prefix.
// All blocks co-resident (196 <= 256 CUs) -> spin cannot deadlock.
__global__ __launch_bounds__(256) void k_scan(
        const int* __restrict__ deg, unsigned long long* __restrict__ partials,
        int* __restrict__ rowptr, int* __restrict__ cursor,
        float* __restrict__ dinv, int n) {
    __shared__ int s[256];
    __shared__ int sprefix;
    const int b = blockIdx.x, t = threadIdx.x;
    const int i = b * 256 + t;
    int v = (i < n) ? deg[i] : 0;
    s[t] = v;
    __syncthreads();
    for (int off = 1; off < 256; off <<= 1) {
        int u = (t >= off) ? s[t - off] : 0;
        __syncthreads();
        s[t] += u;
        __syncthreads();
    }
    if (t == 0) {
        __hip_atomic_store(&partials[b],
                ((unsigned long long)s[255] << 2) | 1ull,
                __ATOMIC_RELEASE, __HIP_MEMORY_SCOPE_AGENT);
        if (b == 0) {
            __hip_atomic_store(&partials[0],
                    ((unsigned long long)s[255] << 2) | 2ull,
                    __ATOMIC_RELEASE, __HIP_MEMORY_SCOPE_AGENT);
            sprefix = 0;
        }
    }
    if (b > 0 && t < 64) {
        int acc = 0;
        int k = b - 1;
        for (;;) {
            int idx = k - t;                    // lane t inspects predecessor idx
            unsigned long long p;
            unsigned st;
            do {
                if (idx >= 0) {
                    p = __hip_atomic_load(&partials[idx],
                            __ATOMIC_ACQUIRE, __HIP_MEMORY_SCOPE_AGENT);
                } else {
                    p = 2ull;                   // virtual prefix 0 past the start
                }
                st = (unsigned)(p & 3ull);
            } while (st == 0);                  // spin until published
            unsigned long long bal = __ballot(st == 2);
            int L = (bal != 0) ? (__ffsll((unsigned long long)bal) - 1) : 64;
            int val = (int)(p >> 2);
            int contrib = (t <= L) ? val : 0;   // aggregates before + prefix at L
            #pragma unroll
            for (int o = 32; o > 0; o >>= 1) contrib += __shfl_down(contrib, o);
            if (t == 0) acc += contrib;
            if (L < 64) break;                  // prefix found in this window
            k -= 64;
        }
        if (t == 0) {
            __hip_atomic_store(&partials[b],
                    (((unsigned long long)(acc + s[255])) << 2) | 2ull,
                    __ATOMIC_RELEASE, __HIP_MEMORY_SCOPE_AGENT);
            sprefix = acc;
        }
    }
    __syncthreads();
    if (i < n) {
        int ex = sprefix + s[t] - v;            // exclusive prefix
        rowptr[i] = ex;
        cursor[i] = ex;
        dinv[i] = rsqrtf((float)(v + 1));       // +1 self-loop
        if (i == n - 1) rowptr[n] = ex + v;
    }
}

// XCD-partitioned scatter (R12): block b serves dst in [(b&7)*n/8, ...).
__global__ __launch_bounds__(256) void k_fill(const int* __restrict__ ei,
                                              int* __restrict__ cursor,
                                              const float* __restrict__ dinv,
                                              int2* __restrict__ csr, int E, int n) {
    const int xcd = blockIdx.x & 7;
    const int e = (blockIdx.x >> 3) * 256 + threadIdx.x;
    if (e >= E) return;
    int d = ei[E + e];
    const int lo = (int)(((long long)xcd * n) >> 3);
    const int hi = (int)(((long long)(xcd + 1) * n) >> 3);
    if (d < lo || d >= hi) return;
    int s = ei[e];
    int pos = atomicAdd(&cursor[d], 1);
    int2 p;
    p.x = s;
    p.y = __float_as_int(dinv[s] * dinv[d]);
    csr[pos] = p;
}

__device__ __forceinline__ ushort_t f2bf_rne(float f) {
    uint_t u = __float_as_uint(f);
    u += 0x7fffu + ((u >> 16) & 1u);
    return (ushort_t)(u >> 16);
}
__device__ __forceinline__ float bflo(uint_t u) {
    return __uint_as_float(u << 16);
}
__device__ __forceinline__ float bfhi(uint_t u) {
    return __uint_as_float(u & 0xffff0000u);
}

// ---- Ybf16[N,128] = X[N,128] @ W[128,128].  BM=128, BK=32; 8x8 microtile.
__global__ __launch_bounds__(256) void k_gemm128(const float* __restrict__ X,
                                                 const float* __restrict__ W,
                                                 ushort_t* __restrict__ Y, int N) {
    __shared__ float sX[32][132];
    __shared__ float sW[32][128];
    const int tid = threadIdx.x;
    const int bm = blockIdx.x * 128;
    const int m0 = (tid >> 4) * 8;
    const int c4 = (tid & 15) * 4;
    const int xf = tid & 7;
    float acc[8][8] = {};
    for (int k0 = 0; k0 < 128; k0 += 32) {
        #pragma unroll
        for (int it = 0; it < 4; ++it) {
            int i = tid + it * 256;
            int row = bm + (i >> 3);
            int rc = min(row, N - 1);
            float4 v = *(const float4*)(X + (size_t)rc * 128 + k0 + xf * 4);
            int m = i >> 3;
            sX[xf * 4 + 0][m] = v.x;
            sX[xf * 4 + 1][m] = v.y;
            sX[xf * 4 + 2][m] = v.z;
            sX[xf * 4 + 3][m] = v.w;
        }
        #pragma unroll
        for (int it = 0; it < 4; ++it) {
            int i = tid + it * 256;
            int wr = i >> 5;
            int wf = i & 31;
            *(float4*)(&sW[wr][wf * 4]) =
                *(const float4*)(W + (size_t)(k0 + wr) * 128 + wf * 4);
        }
        __syncthreads();
        #pragma unroll
        for (int kk = 0; kk < 32; ++kk) {
            float4 a0 = *(const float4*)(&sX[kk][m0]);
            float4 a1 = *(const float4*)(&sX[kk][m0 + 4]);
            float4 b0 = *(const float4*)(&sW[kk][c4]);
            float4 b1 = *(const float4*)(&sW[kk][64 + c4]);
            float av[8] = {a0.x, a0.y, a0.z, a0.w, a1.x, a1.y, a1.z, a1.w};
            float bv[8] = {b0.x, b0.y, b0.z, b0.w, b1.x, b1.y, b1.z, b1.w};
            #pragma unroll
            for (int r = 0; r < 8; ++r)
                #pragma unroll
                for (int c = 0; c < 8; ++c)
                    acc[r][c] = fmaf(av[r], bv[c], acc[r][c]);
        }
        __syncthreads();
    }
    #pragma unroll
    for (int r = 0; r < 8; ++r) {
        int row = bm + m0 + r;
        if (row < N) {
            ushort4 o0 = {f2bf_rne(acc[r][0]), f2bf_rne(acc[r][1]),
                          f2bf_rne(acc[r][2]), f2bf_rne(acc[r][3])};
            ushort4 o1 = {f2bf_rne(acc[r][4]), f2bf_rne(acc[r][5]),
                          f2bf_rne(acc[r][6]), f2bf_rne(acc[r][7])};
            *(ushort4*)(Y + (size_t)row * 128 + c4)      = o0;
            *(ushort4*)(Y + (size_t)row * 128 + 64 + c4) = o1;
        }
    }
}

// ---- Ybf16[N,40 (stride 64)] = X[N,128] @ W[128,40].  BM=128, BK=32. ----
__global__ __launch_bounds__(256) void k_gemm40(const float* __restrict__ X,
                                                const float* __restrict__ W,
                                                ushort_t* __restrict__ Y, int N) {
    __shared__ float sX[32][132];
    __shared__ float sW[32][40];
    const int tid = threadIdx.x;
    const int bm = blockIdx.x * 128;
    const int m0 = (tid >> 3) * 4;
    const int n0 = (tid & 7) * 5;
    const int xf = tid & 7;
    float acc[4][5] = {};
    for (int k0 = 0; k0 < 128; k0 += 32) {
        #pragma unroll
        for (int it = 0; it < 4; ++it) {
            int i = tid + it * 256;
            int row = bm + (i >> 3);
            int rc = min(row, N - 1);
            float4 v = *(const float4*)(X + (size_t)rc * 128 + k0 + xf * 4);
            int m = i >> 3;
            sX[xf * 4 + 0][m] = v.x;
            sX[xf * 4 + 1][m] = v.y;
            sX[xf * 4 + 2][m] = v.z;
            sX[xf * 4 + 3][m] = v.w;
        }
        for (int i = tid; i < 320; i += 256) {
            int wr = i / 10;
            int wf = i - wr * 10;
            *(float4*)(&sW[wr][wf * 4]) =
                *(const float4*)(W + (size_t)(k0 + wr) * 40 + wf * 4);
        }
        __syncthreads();
        #pragma unroll
        for (int kk = 0; kk < 32; ++kk) {
            float4 a = *(const float4*)(&sX[kk][m0]);
            float av[4] = {a.x, a.y, a.z, a.w};
            #pragma unroll
            for (int c = 0; c < 5; ++c) {
                float b = sW[kk][n0 + c];
                #pragma unroll
                for (int r = 0; r < 4; ++r)
                    acc[r][c] = fmaf(av[r], b, acc[r][c]);
            }
        }
        __syncthreads();
    }
    #pragma unroll
    for (int r = 0; r < 4; ++r) {
        int row = bm + m0 + r;
        if (row < N) {
            #pragma unroll
            for (int c = 0; c < 5; ++c)
                Y[(size_t)row * 64 + n0 + c] = f2bf_rne(acc[r][c]);
        }
    }
}

// Uniform full-wave agg, F=128 bf16 (R14 form, unroll 8).
template <bool RELU>
__global__ __launch_bounds__(256) void k_agg128(
        const ushort_t* __restrict__ XW, const int* __restrict__ rowptr,
        const int2* __restrict__ csr, const float* __restrict__ dinv,
        const float* __restrict__ bias, float* __restrict__ out, int n) {
    const int lane = threadIdx.x & 63;
    const int wv = __builtin_amdgcn_readfirstlane(threadIdx.x >> 6);
    const int d = blockIdx.x * 4 + wv;
    if (d >= n) return;
    const uint_t* xw = (const uint_t*)XW;           // row stride 64 uints (256 B)
    float dv = dinv[d];
    float w0 = dv * dv;
    uint_t sq = xw[(size_t)d * 64 + lane];
    float2 a;
    a.x = w0 * bflo(sq);
    a.y = w0 * bfhi(sq);
    int j = rowptr[d], end = rowptr[d + 1];
    for (; j + 8 <= end; j += 8) {
        int2 p0 = csr[j + 0], p1 = csr[j + 1], p2 = csr[j + 2], p3 = csr[j + 3];
        int2 p4 = csr[j + 4], p5 = csr[j + 5], p6 = csr[j + 6], p7 = csr[j + 7];
        uint_t u0 = xw[(size_t)p0.x * 64 + lane];
        uint_t u1 = xw[(size_t)p1.x * 64 + lane];
        uint_t u2 = xw[(size_t)p2.x * 64 + lane];
        uint_t u3 = xw[(size_t)p3.x * 64 + lane];
        uint_t u4 = xw[(size_t)p4.x * 64 + lane];
        uint_t u5 = xw[(size_t)p5.x * 64 + lane];
        uint_t u6 = xw[(size_t)p6.x * 64 + lane];
        uint_t u7 = xw[(size_t)p7.x * 64 + lane];
        float w0e = __int_as_float(p0.y), w1e = __int_as_float(p1.y);
        float w2e = __int_as_float(p2.y), w3e = __int_as_float(p3.y);
        float w4e = __int_as_float(p4.y), w5e = __int_as_float(p5.y);
        float w6e = __int_as_float(p6.y), w7e = __int_as_float(p7.y);
        a.x = fmaf(w0e, bflo(u0), a.x); a.y = fmaf(w0e, bfhi(u0), a.y);
        a.x = fmaf(w1e, bflo(u1), a.x); a.y = fmaf(w1e, bfhi(u1), a.y);
        a.x = fmaf(w2e, bflo(u2), a.x); a.y = fmaf(w2e, bfhi(u2), a.y);
        a.x = fmaf(w3e, bflo(u3), a.x); a.y = fmaf(w3e, bfhi(u3), a.y);
        a.x = fmaf(w4e, bflo(u4), a.x); a.y = fmaf(w4e, bfhi(u4), a.y);
        a.x = fmaf(w5e, bflo(u5), a.x); a.y = fmaf(w5e, bfhi(u5), a.y);
        a.x = fmaf(w6e, bflo(u6), a.x); a.y = fmaf(w6e, bfhi(u6), a.y);
        a.x = fmaf(w7e, bflo(u7), a.x); a.y = fmaf(w7e, bfhi(u7), a.y);
    }
    for (; j < end; ++j) {
        int2 p = csr[j];
        float we = __int_as_float(p.y);
        uint_t u = xw[(size_t)p.x * 64 + lane];
        a.x = fmaf(we, bflo(u), a.x);
        a.y = fmaf(we, bfhi(u), a.y);
    }
    float2 b = ((const float2*)bias)[lane];
    a.x += b.x; a.y += b.y;
    if (RELU) {
        a.x = fmaxf(a.x, 0.f);
        a.y = fmaxf(a.y, 0.f);
    }
    ((float2*)out)[(size_t)d * 64 + lane] = a;
}

// Half-wave per dst, F=40 bf16 rows padded to stride 64 (R14 form).
__global__ __launch_bounds__(256) void k_agg40(
        const ushort_t* __restrict__ XW, const int* __restrict__ rowptr,
        const int2* __restrict__ csr, const float* __restrict__ dinv,
        const float* __restrict__ bias, float* __restrict__ out, int n) {
    const int lane = threadIdx.x & 31;
    const int sub  = threadIdx.x >> 5;
    const int d = blockIdx.x * 8 + sub;
    if (d >= n || lane >= 20) return;
    const uint_t* xw = (const uint_t*)XW;       // row stride 32 uints
    float dv = dinv[d];
    float w0 = dv * dv;
    uint_t sq = xw[(size_t)d * 32 + lane];
    float2 a;
    a.x = w0 * bflo(sq);
    a.y = w0 * bfhi(sq);
    int j = rowptr[d], end = rowptr[d + 1];
    for (; j + 4 <= end; j += 4) {
        int2 p0 = csr[j + 0], p1 = csr[j + 1], p2 = csr[j + 2], p3 = csr[j + 3];
        uint_t u0 = xw[(size_t)p0.x * 32 + lane];
        uint_t u1 = xw[(size_t)p1.x * 32 + lane];
        uint_t u2 = xw[(size_t)p2.x * 32 + lane];
        uint_t u3 = xw[(size_t)p3.x * 32 + lane];
        float w0e = __int_as_float(p0.y), w1e = __int_as_float(p1.y);
        float w2e = __int_as_float(p2.y), w3e = __int_as_float(p3.y);
        a.x = fmaf(w0e, bflo(u0), a.x); a.y = fmaf(w0e, bfhi(u0), a.y);
        a.x = fmaf(w1e, bflo(u1), a.x); a.y = fmaf(w1e, bfhi(u1), a.y);
        a.x = fmaf(w2e, bflo(u2), a.x); a.y = fmaf(w2e, bfhi(u2), a.y);
        a.x = fmaf(w3e, bflo(u3), a.x); a.y = fmaf(w3e, bfhi(u3), a.y);
    }
    for (; j < end; ++j) {
        int2 p = csr[j];
        float we = __int_as_float(p.y);
        uint_t u = xw[(size_t)p.x * 32 + lane];
        a.x = fmaf(we, bflo(u), a.x);
        a.y = fmaf(we, bfhi(u), a.y);
    }
    float2 b = ((const float2*)bias)[lane];
    a.x += b.x; a.y += b.y;
    ((float2*)out)[(size_t)d * 20 + lane] = a;
}

static inline int cdiv(long long a, int b) { return (int)((a + b - 1) / b); }

extern "C" void kernel_launch(void* const* d_in, const int* in_sizes, int n_in,
                              void* d_out, int out_size, void* d_ws, size_t ws_size,
                              hipStream_t stream) {
    const float* x  = (const float*)d_in[0];
    const int*   ei = (const int*)d_in[1];
    const float* W1 = (const float*)d_in[2];
    const float* b1 = (const float*)d_in[3];
    const float* W2 = (const float*)d_in[4];
    const float* b2 = (const float*)d_in[5];
    const float* W3 = (const float*)d_in[6];
    const float* b3 = (const float*)d_in[7];
    float* out = (float*)d_out;

    const int N = in_sizes[0] / 128;   // 50000
    const int E = in_sizes[1] / 2;     // 800000
    const int nb = cdiv(N, 256);       // 196 scan blocks (<=256 CUs: co-resident)

    char* ws = (char*)d_ws;
    int*   deg    = (int*)ws;                 ws += (size_t)N * 4;   // N*4 % 8 == 0
    unsigned long long* partials = (unsigned long long*)ws;
                                              ws += (size_t)nb * 8;
    int*   rowptr = (int*)ws;                 ws += (size_t)(N + 1) * 4;
    int*   cursor = (int*)ws;                 ws += (size_t)N * 4;
    float* dinv   = (float*)ws;               ws += (size_t)N * 4;
    ws = (char*)(((uintptr_t)ws + 127) & ~(uintptr_t)127);
    int2*  csr    = (int2*)ws;                ws += (size_t)E * 8;
    char*  bufA   = ws;                       ws += (size_t)N * 128 * 4;
    float* bufB   = (float*)ws;

    const int BT = 256;

    // CSR build: one memset covers deg AND partials (contiguous).
    hipMemsetAsync(deg, 0, (size_t)N * 4 + (size_t)nb * 8, stream);
    k_deg_count<<<cdiv(E, BT), BT, 0, stream>>>(ei, deg, E);
    k_scan<<<nb, 256, 0, stream>>>(deg, partials, rowptr, cursor, dinv, N);
    k_fill<<<cdiv(E, BT) * 8, 256, 0, stream>>>(ei, cursor, dinv, csr, E, N);

    // layer 1
    k_gemm128<<<cdiv(N, 128), 256, 0, stream>>>(x, W1, (ushort_t*)bufA, N);
    k_agg128<true><<<cdiv(N, 4), 256, 0, stream>>>((const ushort_t*)bufA, rowptr, csr, dinv, b1, bufB, N);
    // layer 2
    k_gemm128<<<cdiv(N, 128), 256, 0, stream>>>(bufB, W2, (ushort_t*)bufA, N);
    k_agg128<true><<<cdiv(N, 4), 256, 0, stream>>>((const ushort_t*)bufA, rowptr, csr, dinv, b2, bufB, N);
    // layer 3 (bf16 staged, rows padded to one 128-B line)
    k_gemm40<<<cdiv(N, 128), 256, 0, stream>>>(bufB, W3, (ushort_t*)bufA, N);
    k_agg40<<<cdiv(N, 8), 256, 0, stream>>>((const ushort_t*)bufA, rowptr, csr, dinv, b3, out, N);
}

// Round 17
// 303.610 us; speedup vs baseline: 1.1803x; 1.0806x over previous
//
#include <hip/hip_runtime.h>

typedef unsigned short ushort_t;
typedef unsigned int uint_t;

// ---------------------------------------------------------------------------
// GCN 3-layer forward.  N=50000, E=800000, D=H=128, C=40.
// Round 17: overlap the only independent pair in the DAG — deg_count (ei
// only) and gemm128-L1 (x,W1 only) — as a block-range UNION kernel: blocks
// [0,gemmGrid) run the GEMM tile, the rest do 1-edge/thread degree atomics.
// The memory-latency-bound counter hides under the compute-bound GEMM
// (m114-style co-scheduling).  Everything else = R16 (wave-parallel lookback
// scan, XCD-partitioned fill, 8B csr, uniform-wave agg128, padded agg40).
// ws layout: [deg:N int][partials:nb u64][rowptr:N+1][cursor:N][dinv:N f32]
//            [csr:E int2][bufA:N*128*4 B][bufB:N*128 f32]
// ---------------------------------------------------------------------------

// Single-dispatch scan, wave-parallel decoupled lookback (R16).
__global__ __launch_bounds__(256) void k_scan(
        const int* __restrict__ deg, unsigned long long* __restrict__ partials,
        int* __restrict__ rowptr, int* __restrict__ cursor,
        float* __restrict__ dinv, int n) {
    __shared__ int s[256];
    __shared__ int sprefix;
    const int b = blockIdx.x, t = threadIdx.x;
    const int i = b * 256 + t;
    int v = (i < n) ? deg[i] : 0;
    s[t] = v;
    __syncthreads();
    for (int off = 1; off < 256; off <<= 1) {
        int u = (t >= off) ? s[t - off] : 0;
        __syncthreads();
        s[t] += u;
        __syncthreads();
    }
    if (t == 0) {
        __hip_atomic_store(&partials[b],
                ((unsigned long long)s[255] << 2) | 1ull,
                __ATOMIC_RELEASE, __HIP_MEMORY_SCOPE_AGENT);
        if (b == 0) {
            __hip_atomic_store(&partials[0],
                    ((unsigned long long)s[255] << 2) | 2ull,
                    __ATOMIC_RELEASE, __HIP_MEMORY_SCOPE_AGENT);
            sprefix = 0;
        }
    }
    if (b > 0 && t < 64) {
        int acc = 0;
        int k = b - 1;
        for (;;) {
            int idx = k - t;
            unsigned long long p;
            unsigned st;
            do {
                if (idx >= 0) {
                    p = __hip_atomic_load(&partials[idx],
                            __ATOMIC_ACQUIRE, __HIP_MEMORY_SCOPE_AGENT);
                } else {
                    p = 2ull;
                }
                st = (unsigned)(p & 3ull);
            } while (st == 0);
            unsigned long long bal = __ballot(st == 2);
            int L = (bal != 0) ? (__ffsll((unsigned long long)bal) - 1) : 64;
            int val = (int)(p >> 2);
            int contrib = (t <= L) ? val : 0;
            #pragma unroll
            for (int o = 32; o > 0; o >>= 1) contrib += __shfl_down(contrib, o);
            if (t == 0) acc += contrib;
            if (L < 64) break;
            k -= 64;
        }
        if (t == 0) {
            __hip_atomic_store(&partials[b],
                    (((unsigned long long)(acc + s[255])) << 2) | 2ull,
                    __ATOMIC_RELEASE, __HIP_MEMORY_SCOPE_AGENT);
            sprefix = acc;
        }
    }
    __syncthreads();
    if (i < n) {
        int ex = sprefix + s[t] - v;
        rowptr[i] = ex;
        cursor[i] = ex;
        dinv[i] = rsqrtf((float)(v + 1));
        if (i == n - 1) rowptr[n] = ex + v;
    }
}

// XCD-partitioned scatter (R12).
__global__ __launch_bounds__(256) void k_fill(const int* __restrict__ ei,
                                              int* __restrict__ cursor,
                                              const float* __restrict__ dinv,
                                              int2* __restrict__ csr, int E, int n) {
    const int xcd = blockIdx.x & 7;
    const int e = (blockIdx.x >> 3) * 256 + threadIdx.x;
    if (e >= E) return;
    int d = ei[E + e];
    const int lo = (int)(((long long)xcd * n) >> 3);
    const int hi = (int)(((long long)(xcd + 1) * n) >> 3);
    if (d < lo || d >= hi) return;
    int s = ei[e];
    int pos = atomicAdd(&cursor[d], 1);
    int2 p;
    p.x = s;
    p.y = __float_as_int(dinv[s] * dinv[d]);
    csr[pos] = p;
}

__device__ __forceinline__ ushort_t f2bf_rne(float f) {
    uint_t u = __float_as_uint(f);
    u += 0x7fffu + ((u >> 16) & 1u);
    return (ushort_t)(u >> 16);
}
__device__ __forceinline__ float bflo(uint_t u) {
    return __uint_as_float(u << 16);
}
__device__ __forceinline__ float bfhi(uint_t u) {
    return __uint_as_float(u & 0xffff0000u);
}

// ---- UNION: blocks [0,gemmGrid) = Ybf16[N,128]=X@W1 (BM=128, 8x8 utile);
//      blocks [gemmGrid, ...) = deg_count (1 edge/thread).  Independent work.
__global__ __launch_bounds__(256) void k_l1(const float* __restrict__ X,
                                            const float* __restrict__ W,
                                            ushort_t* __restrict__ Y, int N,
                                            const int* __restrict__ ei,
                                            int* __restrict__ deg, int E,
                                            int gemmGrid) {
    __shared__ float sX[32][132];
    __shared__ float sW[32][128];
    if ((int)blockIdx.x >= gemmGrid) {
        int e = ((int)blockIdx.x - gemmGrid) * 256 + threadIdx.x;
        if (e < E) atomicAdd(&deg[ei[E + e]], 1);   // dst = ei[E+e]
        return;
    }
    const int tid = threadIdx.x;
    const int bm = blockIdx.x * 128;
    const int m0 = (tid >> 4) * 8;
    const int c4 = (tid & 15) * 4;
    const int xf = tid & 7;
    float acc[8][8] = {};
    for (int k0 = 0; k0 < 128; k0 += 32) {
        #pragma unroll
        for (int it = 0; it < 4; ++it) {
            int i = tid + it * 256;
            int row = bm + (i >> 3);
            int rc = min(row, N - 1);
            float4 v = *(const float4*)(X + (size_t)rc * 128 + k0 + xf * 4);
            int m = i >> 3;
            sX[xf * 4 + 0][m] = v.x;
            sX[xf * 4 + 1][m] = v.y;
            sX[xf * 4 + 2][m] = v.z;
            sX[xf * 4 + 3][m] = v.w;
        }
        #pragma unroll
        for (int it = 0; it < 4; ++it) {
            int i = tid + it * 256;
            int wr = i >> 5;
            int wf = i & 31;
            *(float4*)(&sW[wr][wf * 4]) =
                *(const float4*)(W + (size_t)(k0 + wr) * 128 + wf * 4);
        }
        __syncthreads();
        #pragma unroll
        for (int kk = 0; kk < 32; ++kk) {
            float4 a0 = *(const float4*)(&sX[kk][m0]);
            float4 a1 = *(const float4*)(&sX[kk][m0 + 4]);
            float4 b0 = *(const float4*)(&sW[kk][c4]);
            float4 b1 = *(const float4*)(&sW[kk][64 + c4]);
            float av[8] = {a0.x, a0.y, a0.z, a0.w, a1.x, a1.y, a1.z, a1.w};
            float bv[8] = {b0.x, b0.y, b0.z, b0.w, b1.x, b1.y, b1.z, b1.w};
            #pragma unroll
            for (int r = 0; r < 8; ++r)
                #pragma unroll
                for (int c = 0; c < 8; ++c)
                    acc[r][c] = fmaf(av[r], bv[c], acc[r][c]);
        }
        __syncthreads();
    }
    #pragma unroll
    for (int r = 0; r < 8; ++r) {
        int row = bm + m0 + r;
        if (row < N) {
            ushort4 o0 = {f2bf_rne(acc[r][0]), f2bf_rne(acc[r][1]),
                          f2bf_rne(acc[r][2]), f2bf_rne(acc[r][3])};
            ushort4 o1 = {f2bf_rne(acc[r][4]), f2bf_rne(acc[r][5]),
                          f2bf_rne(acc[r][6]), f2bf_rne(acc[r][7])};
            *(ushort4*)(Y + (size_t)row * 128 + c4)      = o0;
            *(ushort4*)(Y + (size_t)row * 128 + 64 + c4) = o1;
        }
    }
}

// ---- Ybf16[N,128] = X[N,128] @ W[128,128].  BM=128, BK=32; 8x8 microtile.
__global__ __launch_bounds__(256) void k_gemm128(const float* __restrict__ X,
                                                 const float* __restrict__ W,
                                                 ushort_t* __restrict__ Y, int N) {
    __shared__ float sX[32][132];
    __shared__ float sW[32][128];
    const int tid = threadIdx.x;
    const int bm = blockIdx.x * 128;
    const int m0 = (tid >> 4) * 8;
    const int c4 = (tid & 15) * 4;
    const int xf = tid & 7;
    float acc[8][8] = {};
    for (int k0 = 0; k0 < 128; k0 += 32) {
        #pragma unroll
        for (int it = 0; it < 4; ++it) {
            int i = tid + it * 256;
            int row = bm + (i >> 3);
            int rc = min(row, N - 1);
            float4 v = *(const float4*)(X + (size_t)rc * 128 + k0 + xf * 4);
            int m = i >> 3;
            sX[xf * 4 + 0][m] = v.x;
            sX[xf * 4 + 1][m] = v.y;
            sX[xf * 4 + 2][m] = v.z;
            sX[xf * 4 + 3][m] = v.w;
        }
        #pragma unroll
        for (int it = 0; it < 4; ++it) {
            int i = tid + it * 256;
            int wr = i >> 5;
            int wf = i & 31;
            *(float4*)(&sW[wr][wf * 4]) =
                *(const float4*)(W + (size_t)(k0 + wr) * 128 + wf * 4);
        }
        __syncthreads();
        #pragma unroll
        for (int kk = 0; kk < 32; ++kk) {
            float4 a0 = *(const float4*)(&sX[kk][m0]);
            float4 a1 = *(const float4*)(&sX[kk][m0 + 4]);
            float4 b0 = *(const float4*)(&sW[kk][c4]);
            float4 b1 = *(const float4*)(&sW[kk][64 + c4]);
            float av[8] = {a0.x, a0.y, a0.z, a0.w, a1.x, a1.y, a1.z, a1.w};
            float bv[8] = {b0.x, b0.y, b0.z, b0.w, b1.x, b1.y, b1.z, b1.w};
            #pragma unroll
            for (int r = 0; r < 8; ++r)
                #pragma unroll
                for (int c = 0; c < 8; ++c)
                    acc[r][c] = fmaf(av[r], bv[c], acc[r][c]);
        }
        __syncthreads();
    }
    #pragma unroll
    for (int r = 0; r < 8; ++r) {
        int row = bm + m0 + r;
        if (row < N) {
            ushort4 o0 = {f2bf_rne(acc[r][0]), f2bf_rne(acc[r][1]),
                          f2bf_rne(acc[r][2]), f2bf_rne(acc[r][3])};
            ushort4 o1 = {f2bf_rne(acc[r][4]), f2bf_rne(acc[r][5]),
                          f2bf_rne(acc[r][6]), f2bf_rne(acc[r][7])};
            *(ushort4*)(Y + (size_t)row * 128 + c4)      = o0;
            *(ushort4*)(Y + (size_t)row * 128 + 64 + c4) = o1;
        }
    }
}

// ---- Ybf16[N,40 (stride 64)] = X[N,128] @ W[128,40].  BM=128, BK=32. ----
__global__ __launch_bounds__(256) void k_gemm40(const float* __restrict__ X,
                                                const float* __restrict__ W,
                                                ushort_t* __restrict__ Y, int N) {
    __shared__ float sX[32][132];
    __shared__ float sW[32][40];
    const int tid = threadIdx.x;
    const int bm = blockIdx.x * 128;
    const int m0 = (tid >> 3) * 4;
    const int n0 = (tid & 7) * 5;
    const int xf = tid & 7;
    float acc[4][5] = {};
    for (int k0 = 0; k0 < 128; k0 += 32) {
        #pragma unroll
        for (int it = 0; it < 4; ++it) {
            int i = tid + it * 256;
            int row = bm + (i >> 3);
            int rc = min(row, N - 1);
            float4 v = *(const float4*)(X + (size_t)rc * 128 + k0 + xf * 4);
            int m = i >> 3;
            sX[xf * 4 + 0][m] = v.x;
            sX[xf * 4 + 1][m] = v.y;
            sX[xf * 4 + 2][m] = v.z;
            sX[xf * 4 + 3][m] = v.w;
        }
        for (int i = tid; i < 320; i += 256) {
            int wr = i / 10;
            int wf = i - wr * 10;
            *(float4*)(&sW[wr][wf * 4]) =
                *(const float4*)(W + (size_t)(k0 + wr) * 40 + wf * 4);
        }
        __syncthreads();
        #pragma unroll
        for (int kk = 0; kk < 32; ++kk) {
            float4 a = *(const float4*)(&sX[kk][m0]);
            float av[4] = {a.x, a.y, a.z, a.w};
            #pragma unroll
            for (int c = 0; c < 5; ++c) {
                float b = sW[kk][n0 + c];
                #pragma unroll
                for (int r = 0; r < 4; ++r)
                    acc[r][c] = fmaf(av[r], b, acc[r][c]);
            }
        }
        __syncthreads();
    }
    #pragma unroll
    for (int r = 0; r < 4; ++r) {
        int row = bm + m0 + r;
        if (row < N) {
            #pragma unroll
            for (int c = 0; c < 5; ++c)
                Y[(size_t)row * 64 + n0 + c] = f2bf_rne(acc[r][c]);
        }
    }
}

// Uniform full-wave agg, F=128 bf16 (R14 form, unroll 8).
template <bool RELU>
__global__ __launch_bounds__(256) void k_agg128(
        const ushort_t* __restrict__ XW, const int* __restrict__ rowptr,
        const int2* __restrict__ csr, const float* __restrict__ dinv,
        const float* __restrict__ bias, float* __restrict__ out, int n) {
    const int lane = threadIdx.x & 63;
    const int wv = __builtin_amdgcn_readfirstlane(threadIdx.x >> 6);
    const int d = blockIdx.x * 4 + wv;
    if (d >= n) return;
    const uint_t* xw = (const uint_t*)XW;           // row stride 64 uints (256 B)
    float dv = dinv[d];
    float w0 = dv * dv;
    uint_t sq = xw[(size_t)d * 64 + lane];
    float2 a;
    a.x = w0 * bflo(sq);
    a.y = w0 * bfhi(sq);
    int j = rowptr[d], end = rowptr[d + 1];
    for (; j + 8 <= end; j += 8) {
        int2 p0 = csr[j + 0], p1 = csr[j + 1], p2 = csr[j + 2], p3 = csr[j + 3];
        int2 p4 = csr[j + 4], p5 = csr[j + 5], p6 = csr[j + 6], p7 = csr[j + 7];
        uint_t u0 = xw[(size_t)p0.x * 64 + lane];
        uint_t u1 = xw[(size_t)p1.x * 64 + lane];
        uint_t u2 = xw[(size_t)p2.x * 64 + lane];
        uint_t u3 = xw[(size_t)p3.x * 64 + lane];
        uint_t u4 = xw[(size_t)p4.x * 64 + lane];
        uint_t u5 = xw[(size_t)p5.x * 64 + lane];
        uint_t u6 = xw[(size_t)p6.x * 64 + lane];
        uint_t u7 = xw[(size_t)p7.x * 64 + lane];
        float w0e = __int_as_float(p0.y), w1e = __int_as_float(p1.y);
        float w2e = __int_as_float(p2.y), w3e = __int_as_float(p3.y);
        float w4e = __int_as_float(p4.y), w5e = __int_as_float(p5.y);
        float w6e = __int_as_float(p6.y), w7e = __int_as_float(p7.y);
        a.x = fmaf(w0e, bflo(u0), a.x); a.y = fmaf(w0e, bfhi(u0), a.y);
        a.x = fmaf(w1e, bflo(u1), a.x); a.y = fmaf(w1e, bfhi(u1), a.y);
        a.x = fmaf(w2e, bflo(u2), a.x); a.y = fmaf(w2e, bfhi(u2), a.y);
        a.x = fmaf(w3e, bflo(u3), a.x); a.y = fmaf(w3e, bfhi(u3), a.y);
        a.x = fmaf(w4e, bflo(u4), a.x); a.y = fmaf(w4e, bfhi(u4), a.y);
        a.x = fmaf(w5e, bflo(u5), a.x); a.y = fmaf(w5e, bfhi(u5), a.y);
        a.x = fmaf(w6e, bflo(u6), a.x); a.y = fmaf(w6e, bfhi(u6), a.y);
        a.x = fmaf(w7e, bflo(u7), a.x); a.y = fmaf(w7e, bfhi(u7), a.y);
    }
    for (; j < end; ++j) {
        int2 p = csr[j];
        float we = __int_as_float(p.y);
        uint_t u = xw[(size_t)p.x * 64 + lane];
        a.x = fmaf(we, bflo(u), a.x);
        a.y = fmaf(we, bfhi(u), a.y);
    }
    float2 b = ((const float2*)bias)[lane];
    a.x += b.x; a.y += b.y;
    if (RELU) {
        a.x = fmaxf(a.x, 0.f);
        a.y = fmaxf(a.y, 0.f);
    }
    ((float2*)out)[(size_t)d * 64 + lane] = a;
}

// Half-wave per dst, F=40 bf16 rows padded to stride 64 (R14 form).
__global__ __launch_bounds__(256) void k_agg40(
        const ushort_t* __restrict__ XW, const int* __restrict__ rowptr,
        const int2* __restrict__ csr, const float* __restrict__ dinv,
        const float* __restrict__ bias, float* __restrict__ out, int n) {
    const int lane = threadIdx.x & 31;
    const int sub  = threadIdx.x >> 5;
    const int d = blockIdx.x * 8 + sub;
    if (d >= n || lane >= 20) return;
    const uint_t* xw = (const uint_t*)XW;       // row stride 32 uints
    float dv = dinv[d];
    float w0 = dv * dv;
    uint_t sq = xw[(size_t)d * 32 + lane];
    float2 a;
    a.x = w0 * bflo(sq);
    a.y = w0 * bfhi(sq);
    int j = rowptr[d], end = rowptr[d + 1];
    for (; j + 4 <= end; j += 4) {
        int2 p0 = csr[j + 0], p1 = csr[j + 1], p2 = csr[j + 2], p3 = csr[j + 3];
        uint_t u0 = xw[(size_t)p0.x * 32 + lane];
        uint_t u1 = xw[(size_t)p1.x * 32 + lane];
        uint_t u2 = xw[(size_t)p2.x * 32 + lane];
        uint_t u3 = xw[(size_t)p3.x * 32 + lane];
        float w0e = __int_as_float(p0.y), w1e = __int_as_float(p1.y);
        float w2e = __int_as_float(p2.y), w3e = __int_as_float(p3.y);
        a.x = fmaf(w0e, bflo(u0), a.x); a.y = fmaf(w0e, bfhi(u0), a.y);
        a.x = fmaf(w1e, bflo(u1), a.x); a.y = fmaf(w1e, bfhi(u1), a.y);
        a.x = fmaf(w2e, bflo(u2), a.x); a.y = fmaf(w2e, bfhi(u2), a.y);
        a.x = fmaf(w3e, bflo(u3), a.x); a.y = fmaf(w3e, bfhi(u3), a.y);
    }
    for (; j < end; ++j) {
        int2 p = csr[j];
        float we = __int_as_float(p.y);
        uint_t u = xw[(size_t)p.x * 32 + lane];
        a.x = fmaf(we, bflo(u), a.x);
        a.y = fmaf(we, bfhi(u), a.y);
    }
    float2 b = ((const float2*)bias)[lane];
    a.x += b.x; a.y += b.y;
    ((float2*)out)[(size_t)d * 20 + lane] = a;
}

static inline int cdiv(long long a, int b) { return (int)((a + b - 1) / b); }

extern "C" void kernel_launch(void* const* d_in, const int* in_sizes, int n_in,
                              void* d_out, int out_size, void* d_ws, size_t ws_size,
                              hipStream_t stream) {
    const float* x  = (const float*)d_in[0];
    const int*   ei = (const int*)d_in[1];
    const float* W1 = (const float*)d_in[2];
    const float* b1 = (const float*)d_in[3];
    const float* W2 = (const float*)d_in[4];
    const float* b2 = (const float*)d_in[5];
    const float* W3 = (const float*)d_in[6];
    const float* b3 = (const float*)d_in[7];
    float* out = (float*)d_out;

    const int N = in_sizes[0] / 128;   // 50000
    const int E = in_sizes[1] / 2;     // 800000
    const int nb = cdiv(N, 256);       // 196 scan blocks (co-resident)

    char* ws = (char*)d_ws;
    int*   deg    = (int*)ws;                 ws += (size_t)N * 4;
    unsigned long long* partials = (unsigned long long*)ws;
                                              ws += (size_t)nb * 8;
    int*   rowptr = (int*)ws;                 ws += (size_t)(N + 1) * 4;
    int*   cursor = (int*)ws;                 ws += (size_t)N * 4;
    float* dinv   = (float*)ws;               ws += (size_t)N * 4;
    ws = (char*)(((uintptr_t)ws + 127) & ~(uintptr_t)127);
    int2*  csr    = (int2*)ws;                ws += (size_t)E * 8;
    char*  bufA   = ws;                       ws += (size_t)N * 128 * 4;
    float* bufB   = (float*)ws;

    const int BT = 256;
    const int gemmGrid = cdiv(N, 128);          // 391
    const int degGrid  = cdiv(E, BT);           // 3125

    // memset covers deg AND partials (contiguous).
    hipMemsetAsync(deg, 0, (size_t)N * 4 + (size_t)nb * 8, stream);

    // layer-1 GEMM ∪ degree count (independent work, one dispatch)
    k_l1<<<gemmGrid + degGrid, 256, 0, stream>>>(x, W1, (ushort_t*)bufA, N,
                                                 ei, deg, E, gemmGrid);
    // CSR build
    k_scan<<<nb, 256, 0, stream>>>(deg, partials, rowptr, cursor, dinv, N);
    k_fill<<<cdiv(E, BT) * 8, 256, 0, stream>>>(ei, cursor, dinv, csr, E, N);

    // layer 1 aggregation
    k_agg128<true><<<cdiv(N, 4), 256, 0, stream>>>((const ushort_t*)bufA, rowptr, csr, dinv, b1, bufB, N);
    // layer 2
    k_gemm128<<<cdiv(N, 128), 256, 0, stream>>>(bufB, W2, (ushort_t*)bufA, N);
    k_agg128<true><<<cdiv(N, 4), 256, 0, stream>>>((const ushort_t*)bufA, rowptr, csr, dinv, b2, bufB, N);
    // layer 3
    k_gemm40<<<cdiv(N, 128), 256, 0, stream>>>(bufB, W3, (ushort_t*)bufA, N);
    k_agg40<<<cdiv(N, 8), 256, 0, stream>>>((const ushort_t*)bufA, rowptr, csr, dinv, b3, out, N);
}